// Round 7
// baseline (126.708 us; speedup 1.0000x reference)
//
#include <hip/hip_runtime.h>
#include <stdint.h>

#define DIM 512
#define NHEADS 8
#define HDIM 64
#define NBINS 961
#define BATCH 64
#define SEQ 256
#define NTOK (BATCH*SEQ)            // 16384
#define BHND (BATCH*NHEADS*SEQ*HDIM) // 8388608 elements per q/k/v tensor

using bf16x8 = __attribute__((ext_vector_type(8))) short;
using f32x4  = __attribute__((ext_vector_type(4))) float;

__device__ __forceinline__ unsigned short f2bf(float f) {
  unsigned u = __float_as_uint(f);
  u += 0x7FFF + ((u >> 16) & 1);   // round-to-nearest-even
  return (unsigned short)(u >> 16);
}

__device__ __forceinline__ void async16(const void* g, void* lds) {
  __builtin_amdgcn_global_load_lds(
      (const __attribute__((address_space(1))) unsigned int*)g,
      (__attribute__((address_space(3))) unsigned int*)lds,
      16, 0, 0);
}

template<int N> __device__ __forceinline__ void waitv() {
  if constexpr (N == 0) asm volatile("s_waitcnt vmcnt(0)" ::: "memory");
  else if constexpr (N == 3) asm volatile("s_waitcnt vmcnt(3)" ::: "memory");
  else if constexpr (N == 4) asm volatile("s_waitcnt vmcnt(4)" ::: "memory");
}

// ---------------- prep kernels ----------------

__global__ void cast_kernel(const float* __restrict__ in,
                            unsigned short* __restrict__ out, int n4) {
  int i = blockIdx.x * 256 + threadIdx.x;
  if (i >= n4) return;
  float4 f = reinterpret_cast<const float4*>(in)[i];
  ushort4 o;
  o.x = f2bf(f.x); o.y = f2bf(f.y); o.z = f2bf(f.z); o.w = f2bf(f.w);
  reinterpret_cast<ushort4*>(out)[i] = o;
}

// bias stored PERMUTED: pos = h*65536 + n*256 + (m&15)*16 + (m>>4)
__global__ void bias_kernel(const int* __restrict__ idx,
                            const float* __restrict__ rpb,
                            float* __restrict__ bf) {
  int i = blockIdx.x * 256 + threadIdx.x;   // [0, 8*65536)
  if (i >= NHEADS * SEQ * SEQ) return;
  int h = i >> 16;
  int r = i & 65535;
  int n = r >> 8, m = r & 255;
  bf[(size_t)h * 65536 + n * 256 + (m & 15) * 16 + (m >> 4)] = rpb[h * NBINS + idx[r]];
}

// ---------------- m201-style GEMM: C = A(Mx512) * B^T(BNx512) + bias --------
// BM=256, BN=NB*128, BK=64 staged as two K-halves (32 cols each).
// 8 waves (2M x 4N), wave tile 128 x NB*32. Double-buffered LDS.
// 4 phases per K-tile; per phase: {ds_read frags, stage 1 half, [vmcnt],
// barrier, lgkmcnt(0), setprio 16*NB/2 MFMA, barrier}. vmcnt is placed one
// phase before the dependent reads and followed by a barrier (collective
// drain -> no cross-wave global_load_lds race). Prefetch distance = 4 phases.
// Swizzle: 64B k-half rows, chunk ^ ((row>>1)&3) on source + read (2-way, free).

template<int NLOAD>
__device__ __forceinline__ void stage_kh(const unsigned short* __restrict__ X,
                                         int row0, int kk, char* dst, int t) {
#pragma unroll
  for (int i = 0; i < NLOAD; ++i) {
    int q = i * 512 + t;                 // 16B chunk id; row = q>>2, chunk = q&3
    int r = q >> 2, c = q & 3;
    const unsigned short* src = X + (size_t)(row0 + r) * 512 + kk + ((c ^ ((r >> 1) & 3)) << 3);
    async16(src, dst + (size_t)(i * 512 + ((t >> 6) << 6)) * 16);
  }
}

template<int NB, int EPI>   // NB = 128-row B halves (BN = NB*128)
__global__ __launch_bounds__(512, 2) void gemm_k2(
    const unsigned short* __restrict__ A,
    const unsigned short* __restrict__ Bw,
    const float* __restrict__ bias,
    void* __restrict__ outp, int nbn, int cpx) {
  extern __shared__ char gsm[];
  constexpr int ASZ = 16384;            // A k-half: 256 x 32 x 2B
  constexpr int BSZ = NB * 8192;        // B k-half: NB*128 x 32 x 2B
  constexpr int BUF = 2 * ASZ + 2 * BSZ;
  constexpr int NI  = 2 * NB;           // B frags per wave
  constexpr int VW  = 2 + NB;           // steady-state vmcnt
  const int t = threadIdx.x;
  const int lane = t & 63, l15 = lane & 15, lg = lane >> 4;
  const int wv = t >> 6, wm = wv & 1, wn = wv >> 1;
  const int bid = blockIdx.x;
  const int nid = (bid & 7) * cpx + (bid >> 3);     // XCD-chunked, bijective
  const int m0 = (nid / nbn) * 256, n0 = (nid % nbn) * (NB * 128);

  f32x4 acc[8][NI];
  const f32x4 fz = {0.f, 0.f, 0.f, 0.f};
#pragma unroll
  for (int a = 0; a < 8; ++a)
#pragma unroll
    for (int b = 0; b < NI; ++b) acc[a][b] = fz;

  // prologue: all 4 halves of K-tile 0 (issue order = consume order)
  stage_kh<2>(A,  m0, 0,  gsm, t);
  stage_kh<NB>(Bw, n0, 0,  gsm + 2 * ASZ, t);
  stage_kh<2>(A,  m0, 32, gsm + ASZ, t);
  stage_kh<NB>(Bw, n0, 32, gsm + 2 * ASZ + BSZ, t);
  waitv<VW>();                          // k0 halves resident (keep k1 in flight)
  __builtin_amdgcn_s_barrier();

  int cur = 0;
#pragma unroll 1
  for (int T = 0; T < 8; ++T) {
    char* base = gsm + cur * BUF;
    char* nxt  = gsm + (cur ^ 1) * BUF;
    const int kn = (T + 1) * 64;

    bf16x8 av[4], bv[NI];
#pragma unroll
    for (int ph = 0; ph < 4; ++ph) {
      const int kh = ph >> 1, mh = ph & 1;
      char* Ah = base + kh * ASZ;
      char* Bh = base + 2 * ASZ + kh * BSZ;
      // ds_read fragments for this phase
#pragma unroll
      for (int mi = 0; mi < 4; ++mi) {
        int ra = wm * 128 + mh * 64 + mi * 16 + l15;
        av[mi] = *(const bf16x8*)(Ah + ra * 64 + ((lg ^ ((ra >> 1) & 3)) * 16));
      }
      if (mh == 0) {
#pragma unroll
        for (int ni = 0; ni < NI; ++ni) {
          int rb = wn * (NB * 32) + ni * 16 + l15;
          bv[ni] = *(const bf16x8*)(Bh + rb * 64 + ((lg ^ ((rb >> 1) & 3)) * 16));
        }
      }
      // stage one half-tile of K-tile T+1
      if (T < 7) {
        if (ph == 0)      stage_kh<2>(A,  m0, kn,      nxt, t);
        else if (ph == 1) stage_kh<NB>(Bw, n0, kn,      nxt + 2 * ASZ, t);
        else if (ph == 2) stage_kh<2>(A,  m0, kn + 32, nxt + ASZ, t);
        else              stage_kh<NB>(Bw, n0, kn + 32, nxt + 2 * ASZ + BSZ, t);
      }
      // counted vmcnt one phase before dependent reads; barrier = collective drain
      if (ph == 1) { if (T < 7) waitv<VW>(); else waitv<0>(); }   // tile T k1
      if (ph == 3 && T < 7) waitv<VW>();                          // tile T+1 k0
      __builtin_amdgcn_s_barrier();
      asm volatile("s_waitcnt lgkmcnt(0)" ::: "memory");
      __builtin_amdgcn_sched_barrier(0);
      __builtin_amdgcn_s_setprio(1);
#pragma unroll
      for (int mi = 0; mi < 4; ++mi)
#pragma unroll
        for (int ni = 0; ni < NI; ++ni)
          acc[mh * 4 + mi][ni] =
              __builtin_amdgcn_mfma_f32_16x16x32_bf16(av[mi], bv[ni], acc[mh * 4 + mi][ni], 0, 0, 0);
      __builtin_amdgcn_s_setprio(0);
      __builtin_amdgcn_s_barrier();
    }
    cur ^= 1;
  }

#pragma unroll
  for (int MI = 0; MI < 8; ++MI)
#pragma unroll
    for (int ni = 0; ni < NI; ++ni)
#pragma unroll
      for (int r = 0; r < 4; ++r) {
        int row = m0 + wm * 128 + MI * 16 + lg * 4 + r;
        int col = n0 + wn * (NB * 32) + ni * 16 + l15;
        float v = acc[MI][ni][r] + bias[col];
        if (EPI == 0) {
          int which = col >> 9, hd = col & 511;
          int b = row >> 8, n = row & 255;
          ((unsigned short*)outp)[(size_t)which * BHND +
              (((size_t)(b * NHEADS + (hd >> 6)) * SEQ + n) * HDIM) + (hd & 63)] = f2bf(v);
        } else {
          ((float*)outp)[(size_t)row * 512 + col] = v;
        }
      }
}

// ---------------- fused attention ----------------
// 4 waves x 16 query rows; 4 blocks per (b,h); grid 2048; 40 KB LDS ->
// 4 blocks/CU. K fragments straight from global (L2-resident, XCD-grouped).
// V^T in LDS (key+dhi swizzle); P per-wave in LDS with bijective row swizzle.

__global__ __launch_bounds__(256, 4) void attn_kernel(
    const unsigned short* __restrict__ qb,
    const unsigned short* __restrict__ kb,
    const unsigned short* __restrict__ vb,
    const float* __restrict__ biasf,
    unsigned short* __restrict__ aout) {
  extern __shared__ char smem[];
  char* v_s = smem;                     // 32 KB: vT [64 d][256 keys]
  const int t = threadIdx.x, lane = t & 63, w = t >> 6;
  const int l15 = lane & 15, lg = lane >> 4;
  char* P_s = smem + 32768 + w * 2048;  // per-wave [16 rows][64 keys] bf16
  const int nid = (blockIdx.x & 7) * 256 + (blockIdx.x >> 3);
  const int bh = nid >> 2, quarter = nid & 3;
  const int h = bh & 7;
  const int b = bh >> 3;
  const int row0 = quarter * 64 + w * 16;           // this wave's 16 query rows
  const size_t base = (size_t)bh * (SEQ * HDIM);

  // stage V transposed (vT[d][key]); swizzle spreads banks over key AND d>>3
#pragma unroll
  for (int i = 0; i < 8; ++i) {
    int c = i * 256 + t;
    int key = c >> 3, d0 = (c & 7) * 8;
    bf16x8 val = *(const bf16x8*)(vb + base + (size_t)c * 8);
#pragma unroll
    for (int j = 0; j < 8; ++j) {
      int d = d0 + j;
      int term = (((d & 7) ^ ((d >> 3) & 7)) << 4);
      *(short*)(v_s + d * 512 + ((key * 2) ^ term)) = val[j];
    }
  }
  // q fragments from global (L2-resident)
  bf16x8 qa[2];
#pragma unroll
  for (int ks = 0; ks < 2; ++ks)
    qa[ks] = *(const bf16x8*)(qb + base + (size_t)(row0 + l15) * 64 + ks * 32 + lg * 8);

  // scores: S = q . k^T, K fragments straight from global
  const unsigned short* kbase = kb + base;
  f32x4 accs[16];
  const f32x4 fz = {0.f, 0.f, 0.f, 0.f};
#pragma unroll
  for (int c = 0; c < 16; ++c) accs[c] = fz;
#pragma unroll
  for (int cf = 0; cf < 16; ++cf) {
    int key = cf * 16 + l15;
#pragma unroll
    for (int ks = 0; ks < 2; ++ks) {
      bf16x8 kf = *(const bf16x8*)(kbase + (size_t)key * 64 + ks * 32 + lg * 8);
      accs[cf] = __builtin_amdgcn_mfma_f32_16x16x32_bf16(qa[ks], kf, accs[cf], 0, 0, 0);
    }
  }

  // scale + rel-pos bias (permuted layout -> 4x float4 per row)
  const float* bh_ptr = biasf + (size_t)h * 65536;
#pragma unroll
  for (int r = 0; r < 4; ++r) {
    int n = row0 + lg * 4 + r;
    const f32x4* bp = (const f32x4*)(bh_ptr + n * 256 + l15 * 16);
    f32x4 b0 = bp[0], b1 = bp[1], b2 = bp[2], b3 = bp[3];
#pragma unroll
    for (int cf = 0; cf < 16; ++cf) {
      float bb = (cf < 4) ? b0[cf] : (cf < 8) ? b1[cf - 4] : (cf < 12) ? b2[cf - 8] : b3[cf - 12];
      accs[cf][r] = accs[cf][r] * 0.125f + bb;
    }
  }

  // softmax across 256 keys (16 in-lane x 16 lanes)
  float pinv[4];
#pragma unroll
  for (int r = 0; r < 4; ++r) {
    float m = -1e30f;
#pragma unroll
    for (int cf = 0; cf < 16; ++cf) m = fmaxf(m, accs[cf][r]);
#pragma unroll
    for (int off = 1; off < 16; off <<= 1) m = fmaxf(m, __shfl_xor(m, off, 64));
    float s = 0.f;
#pragma unroll
    for (int cf = 0; cf < 16; ++cf) {
      float p = __expf(accs[cf][r] - m);
      accs[cf][r] = p;
      s += p;
    }
#pragma unroll
    for (int off = 1; off < 16; off <<= 1) s += __shfl_xor(s, off, 64);
    pinv[r] = 1.0f / s;
  }

  __syncthreads();   // V_s writes complete (hidden under QK^T + softmax)

  // PV: out = P . V, P staged per-wave through LDS in 64-key chunks
  f32x4 acco[4];
#pragma unroll
  for (int c2 = 0; c2 < 4; ++c2) acco[c2] = fz;

  for (int ch = 0; ch < 4; ++ch) {
#pragma unroll
    for (int cl = 0; cl < 4; ++cl)
#pragma unroll
      for (int r = 0; r < 4; ++r) {
        int rowl = lg * 4 + r;
        int ml = cl * 16 + l15;
        int pterm = (((rowl & 7) ^ ((rowl >> 2) & 2)) << 4);   // bijective over 16 rows
        float p = accs[ch * 4 + cl][r] * pinv[r];
        *(short*)(P_s + rowl * 128 + ((ml * 2) ^ pterm)) = (short)f2bf(p);
      }
#pragma unroll
    for (int ks = 0; ks < 2; ++ks) {
      int rterm = (((l15 & 7) ^ ((l15 >> 2) & 2)) << 4);
      bf16x8 pa = *(const bf16x8*)(P_s + l15 * 128 + ((lg * 16 + ks * 64) ^ rterm));
      int keyb = (ch * 64 + ks * 32 + lg * 8) * 2;
      __builtin_amdgcn_s_setprio(1);
#pragma unroll
      for (int df = 0; df < 4; ++df) {
        int d = df * 16 + l15;
        int term = (((d & 7) ^ ((d >> 3) & 7)) << 4);
        bf16x8 vf = *(const bf16x8*)(v_s + d * 512 + (keyb ^ term));
        acco[df] = __builtin_amdgcn_mfma_f32_16x16x32_bf16(pa, vf, acco[df], 0, 0, 0);
      }
      __builtin_amdgcn_s_setprio(0);
    }
  }

  // write attn output in (b, n, h*64+d) bf16
#pragma unroll
  for (int df = 0; df < 4; ++df)
#pragma unroll
    for (int r = 0; r < 4; ++r) {
      int n = row0 + lg * 4 + r;
      int d = df * 16 + l15;
      aout[((size_t)(b * SEQ + n)) * DIM + h * HDIM + d] = f2bf(acco[df][r]);
    }
}

// ---------------- launch ----------------

extern "C" void kernel_launch(void* const* d_in, const int* in_sizes, int n_in,
                              void* d_out, int out_size, void* d_ws, size_t ws_size,
                              hipStream_t stream) {
  const float* x      = (const float*)d_in[0];
  const int*   rpi    = (const int*)d_in[1];
  const float* qkv_w  = (const float*)d_in[2];
  const float* qkv_b  = (const float*)d_in[3];
  const float* proj_w = (const float*)d_in[4];
  const float* proj_b = (const float*)d_in[5];
  const float* rpb    = (const float*)d_in[6];

  char* ws = (char*)d_ws;
  unsigned short* xb    = (unsigned short*)ws;                  // 16,777,216 B
  unsigned short* wqkv  = (unsigned short*)(ws + 16777216);     //  1,572,864 B
  unsigned short* wproj = (unsigned short*)(ws + 18350080);     //    524,288 B
  float*          biasf = (float*)         (ws + 18874368);     //  2,097,152 B
  unsigned short* qkvb  = (unsigned short*)(ws + 20971520);     // 50,331,648 B (q,k,v)
  unsigned short* aoutb = (unsigned short*)(ws + 71303168);     // 16,777,216 B
  // total ws use: 88,080,384 B

  cast_kernel<<<8192, 256, 0, stream>>>(x, xb, 2097152);
  cast_kernel<<<768, 256, 0, stream>>>(qkv_w, wqkv, 196608);
  cast_kernel<<<256, 256, 0, stream>>>(proj_w, wproj, 65536);
  bias_kernel<<<2048, 256, 0, stream>>>(rpi, rpb, biasf);

  // QKV GEMM: M=16384, N=1536: 64 x 6 = 384 blocks, BN=256
  gemm_k2<2, 0><<<384, 512, 131072, stream>>>(xb, wqkv, qkv_b, (void*)qkvb, 6, 48);

  attn_kernel<<<2048, 256, 40960, stream>>>(qkvb, qkvb + BHND, qkvb + 2 * (size_t)BHND,
                                            biasf, aoutb);

  // proj GEMM: M=16384, N=512: 64 x 4 = 256 blocks, BN=128
  gemm_k2<1, 1><<<256, 512, 98304, stream>>>(aoutb, wproj, proj_b, d_out, 4, 32);
}

// Round 9
// 117.034 us; speedup vs baseline: 1.0827x; 1.0827x over previous
//
#include <hip/hip_runtime.h>
#include <stdint.h>

#define DIM 512
#define NHEADS 8
#define HDIM 64
#define NBINS 961
#define BATCH 64
#define SEQ 256
#define NTOK (BATCH*SEQ)            // 16384
#define BHND (BATCH*NHEADS*SEQ*HDIM) // 8388608 elements per q/k/v tensor

using bf16x8 = __attribute__((ext_vector_type(8))) short;
using f32x4  = __attribute__((ext_vector_type(4))) float;

__device__ __forceinline__ unsigned short f2bf(float f) {
  unsigned u = __float_as_uint(f);
  u += 0x7FFF + ((u >> 16) & 1);   // round-to-nearest-even
  return (unsigned short)(u >> 16);
}

__device__ __forceinline__ void async16(const void* g, void* lds) {
  __builtin_amdgcn_global_load_lds(
      (const __attribute__((address_space(1))) unsigned int*)g,
      (__attribute__((address_space(3))) unsigned int*)lds,
      16, 0, 0);
}

// ---------------- merged prep kernel ----------------
// blocks [0,8192): cast x; [8192,8960): cast qkv_w; [8960,9216): cast proj_w;
// [9216,11264): bias gather (permuted layout:
//   pos = h*65536 + n*256 + (m&15)*16 + (m>>4))

__global__ void prep_kernel(const float* __restrict__ x,
                            const float* __restrict__ qkv_w,
                            const float* __restrict__ proj_w,
                            const int* __restrict__ idx,
                            const float* __restrict__ rpb,
                            unsigned short* __restrict__ xb,
                            unsigned short* __restrict__ wqkv,
                            unsigned short* __restrict__ wproj,
                            float* __restrict__ bf) {
  int bid = blockIdx.x;
  if (bid < 9216) {
    const float* in; unsigned short* out; int i;
    if (bid < 8192)      { in = x;      out = xb;    i = bid * 256 + threadIdx.x; }
    else if (bid < 8960) { in = qkv_w;  out = wqkv;  i = (bid - 8192) * 256 + threadIdx.x; }
    else                 { in = proj_w; out = wproj; i = (bid - 8960) * 256 + threadIdx.x; }
    float4 f = reinterpret_cast<const float4*>(in)[i];
    ushort4 o;
    o.x = f2bf(f.x); o.y = f2bf(f.y); o.z = f2bf(f.z); o.w = f2bf(f.w);
    reinterpret_cast<ushort4*>(out)[i] = o;
  } else {
    int i = (bid - 9216) * 256 + threadIdx.x;   // [0, 8*65536)
    int h = i >> 16;
    int r = i & 65535;
    int n = r >> 8, m = r & 255;
    bf[(size_t)h * 65536 + n * 256 + (m & 15) * 16 + (m >> 4)] = rpb[h * NBINS + idx[r]];
  }
}

// ---------------- 8-wave GEMM: C = A(Mx512) * B^T(BNx512) + bias -----------
// BM=256, BK=64, 8 waves (2M x 4N), wave tile 128 x NBW*16.
// Double-buffered LDS. COLLECTIVE drain: vmcnt(0) BEFORE the head barrier
// (only tile T's 8 loads are outstanding there -> zero lost overlap), then
// s_barrier + sched_barrier(0) pins stages/reads after it.
// EPI 0: q/k scatter into (B,H,N,D) bf16; v written PRE-TRANSPOSED +
//        PRE-SWIZZLED: vT image at byte bh*32768 + d*512 + ((n*2)^((d&7)<<4)).
// EPI 1: fp32 out row-major + bias.

__device__ __forceinline__ void stage_half(const unsigned short* __restrict__ X,
                                           int row0, int kk, char* dst, int t) {
#pragma unroll
  for (int i = 0; i < 2; ++i) {
    int q = i * 512 + t;                 // 16B chunk id 0..1023
    int r = q >> 3, s = q & 7;
    const unsigned short* src = X + (size_t)(row0 + r) * 512 + kk + ((s ^ (r & 7)) << 3);
    async16(src, dst + (size_t)(i * 512 + ((t >> 6) << 6)) * 16);
  }
}

template<int NBW, int EPI>   // NBW = B frags per wave: 4 -> BN=256, 2 -> BN=128
__global__ __launch_bounds__(512) void gemm8p(
    const unsigned short* __restrict__ A,
    const unsigned short* __restrict__ Bw,
    const float* __restrict__ bias,
    void* __restrict__ outp,
    unsigned short* __restrict__ vtb,
    int nbn, int cpx) {
  extern __shared__ char gsm[];
  constexpr int BUF  = 32768 + NBW * 8192;   // A 32KB + B (BN*128 B)
  const int t = threadIdx.x;
  const int lane = t & 63, l15 = lane & 15, lg = lane >> 4;
  const int wv = t >> 6, wm = wv & 1, wn = wv >> 1;
  const int bid = blockIdx.x;
  const int nid = (bid & 7) * cpx + (bid >> 3);       // XCD-chunked, bijective
  const int m0 = (nid / nbn) * 256, n0 = (nid % nbn) * (NBW * 64);

  f32x4 acc[8][NBW];
  const f32x4 fz = {0.f, 0.f, 0.f, 0.f};
#pragma unroll
  for (int a = 0; a < 8; ++a)
#pragma unroll
    for (int b = 0; b < NBW; ++b) acc[a][b] = fz;

  // prologue: all units of K-tile 0 into buf 0
  stage_half(A,  m0,       0, gsm,          t);
  stage_half(A,  m0 + 128, 0, gsm + 16384,  t);
  stage_half(Bw, n0,       0, gsm + 32768,  t);
  if (NBW == 4) stage_half(Bw, n0 + 128, 0, gsm + 49152, t);

  int cur = 0;
#pragma unroll 1
  for (int T = 0; T < 8; ++T) {
    char* Ab  = gsm + cur * BUF;
    char* Bb  = Ab + 32768;
    char* nxt = gsm + (cur ^ 1) * BUF;

    // collective drain of tile T's stages: every wave drains BEFORE the
    // barrier, so after the barrier ALL waves' tile-T chunks are resident.
    asm volatile("s_waitcnt vmcnt(0)" ::: "memory");
    __builtin_amdgcn_s_barrier();        // also: all waves done reading buf^1
    __builtin_amdgcn_sched_barrier(0);   // pin stages/reads below the barrier

    if (T < 7) {
      stage_half(A, m0,       (T + 1) * 64, nxt,         t);
      stage_half(A, m0 + 128, (T + 1) * 64, nxt + 16384, t);
    }
    __builtin_amdgcn_sched_barrier(0);

#pragma unroll
    for (int ph = 0; ph < 4; ++ph) {
      const int kh = ph >> 1, mh = ph & 1;
      if (ph == 1 && T < 7) stage_half(Bw, n0, (T + 1) * 64, nxt + 32768, t);
      if (NBW == 4 && ph == 2 && T < 7) stage_half(Bw, n0 + 128, (T + 1) * 64, nxt + 49152, t);

      const int sw = ((kh * 4 + lg) ^ (l15 & 7)) * 16;
      bf16x8 av[4], bv[NBW];
#pragma unroll
      for (int mi = 0; mi < 4; ++mi)
        av[mi] = *(const bf16x8*)(Ab + wm * 16384 + (mh * 64 + mi * 16 + l15) * 128 + sw);
#pragma unroll
      for (int ni = 0; ni < NBW; ++ni) {
        int rb = wn * (NBW * 16) + ni * 16 + l15;       // B row (= C col) in tile
        bv[ni] = *(const bf16x8*)(Bb + (rb >> 7) * 16384 + (rb & 127) * 128 + sw);
      }
      asm volatile("s_waitcnt lgkmcnt(0)" ::: "memory");
      __builtin_amdgcn_sched_barrier(0);
      __builtin_amdgcn_s_setprio(1);
#pragma unroll
      for (int mi = 0; mi < 4; ++mi)
#pragma unroll
        for (int ni = 0; ni < NBW; ++ni)
          acc[mh * 4 + mi][ni] =
              __builtin_amdgcn_mfma_f32_16x16x32_bf16(av[mi], bv[ni], acc[mh * 4 + mi][ni], 0, 0, 0);
      __builtin_amdgcn_s_setprio(0);
      __builtin_amdgcn_sched_barrier(0);
    }
    cur ^= 1;
  }

#pragma unroll
  for (int MI = 0; MI < 8; ++MI)
#pragma unroll
    for (int ni = 0; ni < NBW; ++ni)
#pragma unroll
      for (int r = 0; r < 4; ++r) {
        int row = m0 + wm * 128 + MI * 16 + lg * 4 + r;
        int col = n0 + wn * (NBW * 16) + ni * 16 + l15;
        float v = acc[MI][ni][r] + bias[col];
        if (EPI == 0) {
          int which = col >> 9, hd = col & 511;
          int b = row >> 8, n = row & 255;
          if (which == 2) {
            // pre-transposed + pre-swizzled vT image
            int h = hd >> 6, d = hd & 63;
            int bh2 = b * NHEADS + h;
            int byteoff = d * 512 + ((n * 2) ^ ((d & 7) << 4));
            vtb[(size_t)bh2 * 16384 + (byteoff >> 1)] = f2bf(v);
          } else {
            ((unsigned short*)outp)[(size_t)which * BHND +
                (((size_t)(b * NHEADS + (hd >> 6)) * SEQ + n) * HDIM) + (hd & 63)] = f2bf(v);
          }
        } else {
          ((float*)outp)[(size_t)row * 512 + col] = v;
        }
      }
}

// ---------------- fused attention ----------------
// 4 waves x 16 query rows; 4 blocks per (b,h); grid 2048 (XCD-chunked).
// K staged to LDS (XOR swizzle, vector writes); V staged via global_load_lds
// from the pre-swizzled vT image (stays in flight under QK^T);
// P reuses the k_s region after QK^T (bijective row swizzle). 64 KB LDS.
// First sync is a PINNED raw barrier (lgkmcnt + sched_barrier + s_barrier +
// sched_barrier): real fence semantics without draining the V vmcnt.

__global__ __launch_bounds__(256) void attn_kernel(
    const unsigned short* __restrict__ qb,
    const unsigned short* __restrict__ kb,
    const char* __restrict__ vtb,      // byte base of swizzled vT image
    const float* __restrict__ biasf,
    unsigned short* __restrict__ aout) {
  extern __shared__ char smem[];
  char* k_s = smem;               // 32 KB: [256 keys][64 d] bf16, XOR-swizzled rows
  char* v_s = smem + 32768;       // 32 KB: vT [64 d][256 keys] bf16, (d&7) swizzle
  const int t = threadIdx.x, lane = t & 63, w = t >> 6;
  const int l15 = lane & 15, lg = lane >> 4;
  char* P_s = smem + w * 2048;    // per-wave [16 rows][64 keys] bf16 — reuses k_s
  const int nid = (blockIdx.x & 7) * 256 + (blockIdx.x >> 3);
  const int bh = nid >> 2, quarter = nid & 3;
  const int h = bh & 7;
  const int b = bh >> 3;
  const int row0 = quarter * 64 + w * 16;           // this wave's 16 query rows
  const size_t base = (size_t)bh * (SEQ * HDIM);

  // 1) K global loads (8 x b128)
  bf16x8 kreg[8];
#pragma unroll
  for (int i = 0; i < 8; ++i)
    kreg[i] = *(const bf16x8*)(kb + base + (size_t)(i * 256 + t) * 8);
  // 2) Q fragments
  bf16x8 qa[2];
#pragma unroll
  for (int ks = 0; ks < 2; ++ks)
    qa[ks] = *(const bf16x8*)(qb + base + (size_t)(row0 + l15) * 64 + ks * 32 + lg * 8);
  // 3) V async global->LDS (pre-swizzled image; linear copy; stays in flight)
  const char* vsrc = vtb + (size_t)bh * 32768;
#pragma unroll
  for (int i = 0; i < 8; ++i) {
    int c = i * 256 + t;
    async16(vsrc + (size_t)c * 16, v_s + c * 16);
  }
  // 4) K -> LDS (vector writes, XOR swizzle); waits K loads only (V younger)
#pragma unroll
  for (int i = 0; i < 8; ++i) {
    int c = i * 256 + t;
    int row = c >> 3, sl = c & 7;
    *(bf16x8*)(k_s + row * 128 + ((sl * 16) ^ ((row & 7) << 4))) = kreg[i];
  }
  asm volatile("s_waitcnt lgkmcnt(0)" ::: "memory");
  __builtin_amdgcn_sched_barrier(0);
  __builtin_amdgcn_s_barrier();     // k_s visible; V loads STILL outstanding
  __builtin_amdgcn_sched_barrier(0);  // pin QK^T ds_reads BELOW the barrier

  // scores: S = q . k^T   (wave owns 16 query rows x 256 keys)
  f32x4 accs[16];
  const f32x4 fz = {0.f, 0.f, 0.f, 0.f};
#pragma unroll
  for (int c = 0; c < 16; ++c) accs[c] = fz;
  __builtin_amdgcn_s_setprio(1);
#pragma unroll
  for (int cf = 0; cf < 16; ++cf) {
    int key = cf * 16 + l15;
#pragma unroll
    for (int ks = 0; ks < 2; ++ks) {
      bf16x8 kf = *(const bf16x8*)(k_s + key * 128 + ((lg * 16 + ks * 64) ^ ((key & 7) << 4)));
      accs[cf] = __builtin_amdgcn_mfma_f32_16x16x32_bf16(qa[ks], kf, accs[cf], 0, 0, 0);
    }
  }
  __builtin_amdgcn_s_setprio(0);

  // scale + rel-pos bias (permuted layout -> 4x float4 per row)
  const float* bh_ptr = biasf + (size_t)h * 65536;
#pragma unroll
  for (int r = 0; r < 4; ++r) {
    int n = row0 + lg * 4 + r;
    const f32x4* bp = (const f32x4*)(bh_ptr + n * 256 + l15 * 16);
    f32x4 b0 = bp[0], b1 = bp[1], b2 = bp[2], b3 = bp[3];
#pragma unroll
    for (int cf = 0; cf < 16; ++cf) {
      float bb = (cf < 4) ? b0[cf] : (cf < 8) ? b1[cf - 4] : (cf < 12) ? b2[cf - 8] : b3[cf - 12];
      accs[cf][r] = accs[cf][r] * 0.125f + bb;
    }
  }

  // softmax across 256 keys (16 in-lane x 16 lanes)
  float pinv[4];
#pragma unroll
  for (int r = 0; r < 4; ++r) {
    float m = -1e30f;
#pragma unroll
    for (int cf = 0; cf < 16; ++cf) m = fmaxf(m, accs[cf][r]);
#pragma unroll
    for (int off = 1; off < 16; off <<= 1) m = fmaxf(m, __shfl_xor(m, off, 64));
    float s = 0.f;
#pragma unroll
    for (int cf = 0; cf < 16; ++cf) {
      float p = __expf(accs[cf][r] - m);
      accs[cf][r] = p;
      s += p;
    }
#pragma unroll
    for (int off = 1; off < 16; off <<= 1) s += __shfl_xor(s, off, 64);
    pinv[r] = 1.0f / s;
  }

  __syncthreads();   // full fence: drains vmcnt(0) -> V resident; k_s reads done

  // PV: out = P . V, P staged per-wave through LDS (k_s region) in 64-key chunks
  f32x4 acco[4];
#pragma unroll
  for (int c2 = 0; c2 < 4; ++c2) acco[c2] = fz;

  for (int ch = 0; ch < 4; ++ch) {
#pragma unroll
    for (int cl = 0; cl < 4; ++cl)
#pragma unroll
      for (int r = 0; r < 4; ++r) {
        int rowl = lg * 4 + r;
        int ml = cl * 16 + l15;
        int pterm = (((rowl & 7) ^ ((rowl >> 2) & 2)) << 4);   // bijective over 16 rows
        float p = accs[ch * 4 + cl][r] * pinv[r];
        *(short*)(P_s + rowl * 128 + ((ml * 2) ^ pterm)) = (short)f2bf(p);
      }
#pragma unroll
    for (int ks = 0; ks < 2; ++ks) {
      int rterm = (((l15 & 7) ^ ((l15 >> 2) & 2)) << 4);
      bf16x8 pa = *(const bf16x8*)(P_s + l15 * 128 + ((lg * 16 + ks * 64) ^ rterm));
      int keyb = (ch * 64 + ks * 32 + lg * 8) * 2;
      __builtin_amdgcn_s_setprio(1);
#pragma unroll
      for (int df = 0; df < 4; ++df) {
        int d = df * 16 + l15;
        bf16x8 vf = *(const bf16x8*)(v_s + d * 512 + (keyb ^ ((d & 7) << 4)));
        acco[df] = __builtin_amdgcn_mfma_f32_16x16x32_bf16(pa, vf, acco[df], 0, 0, 0);
      }
      __builtin_amdgcn_s_setprio(0);
    }
  }

  // write attn output in (b, n, h*64+d) bf16
#pragma unroll
  for (int df = 0; df < 4; ++df)
#pragma unroll
    for (int r = 0; r < 4; ++r) {
      int n = row0 + lg * 4 + r;
      int d = df * 16 + l15;
      aout[((size_t)(b * SEQ + n)) * DIM + h * HDIM + d] = f2bf(acco[df][r]);
    }
}

// ---------------- launch ----------------

extern "C" void kernel_launch(void* const* d_in, const int* in_sizes, int n_in,
                              void* d_out, int out_size, void* d_ws, size_t ws_size,
                              hipStream_t stream) {
  const float* x      = (const float*)d_in[0];
  const int*   rpi    = (const int*)d_in[1];
  const float* qkv_w  = (const float*)d_in[2];
  const float* qkv_b  = (const float*)d_in[3];
  const float* proj_w = (const float*)d_in[4];
  const float* proj_b = (const float*)d_in[5];
  const float* rpb    = (const float*)d_in[6];

  char* ws = (char*)d_ws;
  unsigned short* xb    = (unsigned short*)ws;                  // 16,777,216 B
  unsigned short* wqkv  = (unsigned short*)(ws + 16777216);     //  1,572,864 B
  unsigned short* wproj = (unsigned short*)(ws + 18350080);     //    524,288 B
  float*          biasf = (float*)         (ws + 18874368);     //  2,097,152 B
  unsigned short* qkvb  = (unsigned short*)(ws + 20971520);     // 50,331,648 B (q,k,vT)
  unsigned short* aoutb = (unsigned short*)(ws + 71303168);     // 16,777,216 B
  unsigned short* vtb   = qkvb + 2 * (size_t)BHND;              // vT swizzled image

  prep_kernel<<<11264, 256, 0, stream>>>(x, qkv_w, proj_w, rpi, rpb,
                                         xb, wqkv, wproj, biasf);

  // QKV GEMM: M=16384, N=1536 -> 64 x 6 = 384 blocks, BN=256
  gemm8p<4, 0><<<384, 512, 131072, stream>>>(xb, wqkv, qkv_b, (void*)qkvb, vtb, 6, 48);

  attn_kernel<<<2048, 256, 65536, stream>>>(qkvb, qkvb + BHND, (const char*)vtb,
                                            biasf, aoutb);

  // proj GEMM: M=16384, N=512 -> 64 x 4 = 256 blocks, BN=128
  gemm8p<2, 1><<<256, 512, 98304, stream>>>(aoutb, wproj, proj_b, d_out, nullptr, 4, 32);
}